// Round 8
// baseline (156.038 us; speedup 1.0000x reference)
//
#include <hip/hip_runtime.h>
#include <hip/hip_bf16.h>

constexpr int S  = 2048;
constexpr int C  = 64;
constexpr int NH = 8;
constexpr int HD = 64;
constexpr int TD = 512;
constexpr int FF = 1024;
constexpr int NB = 2;
constexpr int SPLIT  = 4;
constexpr int KTILES = S / SPLIT / 64;   // 8

typedef __bf16 bf16x8 __attribute__((ext_vector_type(8)));
typedef float  f32x4  __attribute__((ext_vector_type(4)));

__device__ __forceinline__ f32x4 mfma16(bf16x8 a, bf16x8 b, f32x4 c) {
  return __builtin_amdgcn_mfma_f32_16x16x32_bf16(a, b, c, 0, 0, 0);
}

__device__ __forceinline__ unsigned int pack_bf2(float a, float b) {
  unsigned short ua = __builtin_bit_cast(unsigned short, (__bf16)a);
  unsigned short ub = __builtin_bit_cast(unsigned short, (__bf16)b);
  return (unsigned int)ua | ((unsigned int)ub << 16);
}

__device__ __forceinline__ float bfu2f(unsigned int u) {
  return __builtin_bit_cast(float, (u & 0xffffu) << 16);
}

// Panel layout: frag[p][ks][lane][8], elem = M[p*16 + (l&15)][ks*32 + (l>>4)*8 + j].
// A wave's fragment load = one contiguous 1KB chunk.

// ---------------------------------------------------------------------------
// Fused preprocessing: blocks 0..335 convert the 5 weight matrices to panel
// layout; blocks 336..463 transpose/convert x -> xbf panels.
// ---------------------------------------------------------------------------
__device__ __forceinline__ void cvt_panel(const float* __restrict__ src,
                                          __hip_bfloat16* __restrict__ dst,
                                          int off, int Wd) {
  const int w8 = Wd >> 3;
  const int r  = off / w8;
  const int k8 = off - r * w8;
  const float4 v0 = *(const float4*)(src + (size_t)r * Wd + k8 * 8);
  const float4 v1 = *(const float4*)(src + (size_t)r * Wd + k8 * 8 + 4);
  const int dc = ((r >> 4) * (Wd >> 5) + (k8 >> 2)) * 64 + (k8 & 3) * 16 + (r & 15);
  uint4 pk;
  pk.x = pack_bf2(v0.x, v0.y); pk.y = pack_bf2(v0.z, v0.w);
  pk.z = pack_bf2(v1.x, v1.y); pk.w = pack_bf2(v1.z, v1.w);
  *(uint4*)&dst[dc * 8] = pk;
}

__global__ __launch_bounds__(256) void k_pre(
    const float* __restrict__ Wq, const float* __restrict__ Wk,
    const float* __restrict__ Wv, const float* __restrict__ W1,
    const float* __restrict__ W2, const float* __restrict__ x,
    __hip_bfloat16* __restrict__ Wqf, __hip_bfloat16* __restrict__ Wkf,
    __hip_bfloat16* __restrict__ Wvf, __hip_bfloat16* __restrict__ W1f,
    __hip_bfloat16* __restrict__ W2f, __hip_bfloat16* __restrict__ xbf) {
  const int b = blockIdx.x;
  if (b < 336) {
    const int q = b * 256 + threadIdx.x;   // 0..86015
    if      (q < 4096)  cvt_panel(Wq, Wqf, q,         C);    // 512x64
    else if (q < 8192)  cvt_panel(Wk, Wkf, q - 4096,  C);
    else if (q < 12288) cvt_panel(Wv, Wvf, q - 8192,  C);
    else if (q < 77824) cvt_panel(W1, W1f, q - 12288, TD);   // 1024x512
    else                cvt_panel(W2, W2f, q - 77824, FF);   // 64x1024
  } else {
    const int id = (b - 336) * 256 + threadIdx.x;  // 0..32767
    const int k8 = id >> 12;
    const int m  = id & 4095;
    const int n  = m >> 11, s = m & 2047;
    float v[8];
    #pragma unroll
    for (int j = 0; j < 8; ++j)
      v[j] = x[(size_t)(n * C + k8 * 8 + j) * S + s];
    const int p = m >> 4, ks = k8 >> 2, l = (m & 15) + (k8 & 3) * 16;
    uint4 pk;
    pk.x = pack_bf2(v[0], v[1]); pk.y = pack_bf2(v[2], v[3]);
    pk.z = pack_bf2(v[4], v[5]); pk.w = pack_bf2(v[6], v[7]);
    *(uint4*)&xbf[((p * 2 + ks) * 64 + l) * 8] = pk;
  }
}

// ---------------------------------------------------------------------------
// QKV projection; panel layout in and out. Q scaled by log2(e)/8.
// ---------------------------------------------------------------------------
__global__ __launch_bounds__(256) void k_qkv(
    const __hip_bfloat16* __restrict__ xbf,
    const __hip_bfloat16* __restrict__ Wqf, const float* __restrict__ bq,
    const __hip_bfloat16* __restrict__ Wkf, const float* __restrict__ bk,
    const __hip_bfloat16* __restrict__ Wvf, const float* __restrict__ bv,
    __hip_bfloat16* __restrict__ Qf, __hip_bfloat16* __restrict__ Kf,
    __hip_bfloat16* __restrict__ Vf) {
  const int t = threadIdx.x, w = t >> 6, l = t & 63;
  const int c = l & 15, g = l >> 4;
  const int m0 = blockIdx.y * 64 + w * 16;
  const int xcol = blockIdx.x, which = xcol >> 3, h = xcol & 7;

  const __hip_bfloat16* Wf = (which == 0) ? Wqf : (which == 1) ? Wkf : Wvf;
  const float*        bias = (which == 0) ? bq  : (which == 1) ? bk  : bv;

  f32x4 acc[4];
  #pragma unroll
  for (int i = 0; i < 4; ++i) acc[i] = f32x4{0.f, 0.f, 0.f, 0.f};

  #pragma unroll
  for (int ks = 0; ks < 2; ++ks) {
    const bf16x8 af = *(const bf16x8*)&xbf[(((m0 >> 4) * 2 + ks) * 64 + l) * 8];
    #pragma unroll
    for (int dt = 0; dt < 4; ++dt) {
      const bf16x8 wf =
          *(const bf16x8*)&Wf[(((h * 4 + dt) * 2 + ks) * 64 + l) * 8];
      acc[dt] = mfma16(wf, af, acc[dt]);  // out[m0+c][h*64 + dt*16 + 4g + r]
    }
  }

  const int m = m0 + c;
  const int nb_ = m >> 11, s = m & 2047;
  const size_t hbq = (size_t)(nb_ * 8 + h) * (S * HD);

  if (which < 2) {
    const float scl = (which == 0) ? 0.1803368801f : 1.0f;  // log2(e)/8
    __hip_bfloat16* Of = ((which == 0) ? Qf : Kf) + hbq;
    const int sp16 = s >> 4;
    #pragma unroll
    for (int dt = 0; dt < 4; ++dt) {
      const int ks = dt >> 1;
      const int lw = c + ((dt & 1) * 2 + (g >> 1)) * 16;
      const int jb = (4 * g) & 7;
      const int d0 = dt * 16 + 4 * g;
      uint2 pk;
      pk.x = pack_bf2((acc[dt][0] + bias[h * 64 + d0 + 0]) * scl,
                      (acc[dt][1] + bias[h * 64 + d0 + 1]) * scl);
      pk.y = pack_bf2((acc[dt][2] + bias[h * 64 + d0 + 2]) * scl,
                      (acc[dt][3] + bias[h * 64 + d0 + 3]) * scl);
      *(uint2*)&Of[((sp16 * 2 + ks) * 64 + lw) * 8 + jb] = pk;
    }
  } else {
    __hip_bfloat16* Vfh = Vf + hbq;
    const int kc = s >> 5, jj = s & 7, lhi = ((s & 31) >> 3) * 16;
    #pragma unroll
    for (int dt = 0; dt < 4; ++dt)
      #pragma unroll
      for (int r = 0; r < 4; ++r) {
        const float v = acc[dt][r] + bias[h * 64 + dt * 16 + 4 * g + r];
        Vfh[((dt * 64 + kc) * 64 + (4 * g + r + lhi)) * 8 + jj] =
            __float2bfloat16(v);
      }
  }
}

// ---------------------------------------------------------------------------
// Flash attention. 2 waves/block, QBLK=32/wave, SPLIT=4. Parity-double-
// buffered P_lds (one wave_barrier/tile). No max subtraction. Softmax
// denominator l computed via MFMA with all-ones B (replaces VALU adds +
// epilogue shuffles). s_setprio(1) around MFMA clusters.
// ---------------------------------------------------------------------------
__global__ __launch_bounds__(128, 4) void k_attn(
    const __hip_bfloat16* __restrict__ Qf,
    const __hip_bfloat16* __restrict__ Kf,
    const __hip_bfloat16* __restrict__ Vf,
    __hip_bfloat16* __restrict__ Opart, float* __restrict__ Lpart) {
  __shared__ unsigned short P_lds[2][2][2][16][72];  // [par][w][qq]

  const int t = threadIdx.x, w = t >> 6, l = t & 63;
  const int c = l & 15, g = l >> 4;
  const int bid = blockIdx.x;
  const int hb  = bid & 15;
  const int sp  = (bid >> 4) & (SPLIT - 1);
  const int q0  = (bid >> 6) * 64 + w * 32;
  const size_t hbase = (size_t)hb * (S * HD);

  bf16x8 ones;
  #pragma unroll
  for (int j = 0; j < 8; ++j) ones[j] = (__bf16)1.0f;

  bf16x8 qf[2][2];
  const int qp0 = q0 >> 4;
  #pragma unroll
  for (int qq = 0; qq < 2; ++qq)
    #pragma unroll
    for (int ks = 0; ks < 2; ++ks)
      qf[qq][ks] =
          *(const bf16x8*)&Qf[hbase + (((qp0 + qq) * 2 + ks) * 64 + l) * 8];

  f32x4 o[2][4];
  f32x4 ol[2];
  #pragma unroll
  for (int qq = 0; qq < 2; ++qq) {
    ol[qq] = f32x4{0.f, 0.f, 0.f, 0.f};
    #pragma unroll
    for (int i = 0; i < 4; ++i) o[qq][i] = f32x4{0.f, 0.f, 0.f, 0.f};
  }

  const int kb = sp * (S / SPLIT);

  #pragma unroll
  for (int it = 0; it < KTILES; ++it) {
    const int k0  = kb + it * 64;
    const int par = it & 1;
    const int kp0 = k0 >> 4, kc0 = k0 >> 5;

    // ---- QK^T (swapped): st[qq][t4][r] = S^T[kv=t4*16+4g+r][q=q0+qq*16+c]
    f32x4 st[2][4];
    #pragma unroll
    for (int qq = 0; qq < 2; ++qq)
      #pragma unroll
      for (int i = 0; i < 4; ++i) st[qq][i] = f32x4{0.f, 0.f, 0.f, 0.f};
    __builtin_amdgcn_s_setprio(1);
    #pragma unroll
    for (int t4 = 0; t4 < 4; ++t4) {
      const bf16x8 ka0 =
          *(const bf16x8*)&Kf[hbase + (((kp0 + t4) * 2 + 0) * 64 + l) * 8];
      const bf16x8 ka1 =
          *(const bf16x8*)&Kf[hbase + (((kp0 + t4) * 2 + 1) * 64 + l) * 8];
      st[0][t4] = mfma16(ka0, qf[0][0], st[0][t4]);
      st[0][t4] = mfma16(ka1, qf[0][1], st[0][t4]);
      st[1][t4] = mfma16(ka0, qf[1][0], st[1][t4]);
      st[1][t4] = mfma16(ka1, qf[1][1], st[1][t4]);
    }
    __builtin_amdgcn_s_setprio(0);

    // ---- P = exp2(s) (no max), P^T scatter into parity buffer
    #pragma unroll
    for (int qq = 0; qq < 2; ++qq)
      #pragma unroll
      for (int t4 = 0; t4 < 4; ++t4) {
        const float e0 = __builtin_amdgcn_exp2f(st[qq][t4][0]);
        const float e1 = __builtin_amdgcn_exp2f(st[qq][t4][1]);
        const float e2 = __builtin_amdgcn_exp2f(st[qq][t4][2]);
        const float e3 = __builtin_amdgcn_exp2f(st[qq][t4][3]);
        uint2 pk;
        pk.x = pack_bf2(e0, e1);
        pk.y = pack_bf2(e2, e3);
        *(uint2*)&P_lds[par][w][qq][c][t4 * 16 + g * 4] = pk;
      }

    __builtin_amdgcn_wave_barrier();   // write->read ordering (wave-local)

    // ---- PV (+ l via ones-MFMA): o[qq][dt] += P[q][kv] * V^T[d][kv]
    __builtin_amdgcn_s_setprio(1);
    #pragma unroll
    for (int ks = 0; ks < 2; ++ks) {
      const bf16x8 pf0 = *(const bf16x8*)&P_lds[par][w][0][c][ks * 32 + g * 8];
      const bf16x8 pf1 = *(const bf16x8*)&P_lds[par][w][1][c][ks * 32 + g * 8];
      ol[0] = mfma16(pf0, ones, ol[0]);
      ol[1] = mfma16(pf1, ones, ol[1]);
      #pragma unroll
      for (int dt = 0; dt < 4; ++dt) {
        const bf16x8 vfr =
            *(const bf16x8*)&Vf[hbase + ((dt * 64 + kc0 + ks) * 64 + l) * 8];
        o[0][dt] = mfma16(pf0, vfr, o[0][dt]);
        o[1][dt] = mfma16(pf1, vfr, o[1][dt]);
      }
    }
    __builtin_amdgcn_s_setprio(0);
    // no trailing barrier: next iteration writes the other parity buffer
  }

  const size_t prow = ((size_t)sp * 16 + hb) * S;
  #pragma unroll
  for (int qq = 0; qq < 2; ++qq) {
    #pragma unroll
    for (int r = 0; r < 4; ++r) {
      __hip_bfloat16* Op = Opart + (prow + q0 + qq * 16 + 4 * g + r) * HD + c;
      Op[0]  = __float2bfloat16(o[qq][0][r]);
      Op[16] = __float2bfloat16(o[qq][1][r]);
      Op[32] = __float2bfloat16(o[qq][2][r]);
      Op[48] = __float2bfloat16(o[qq][3][r]);
    }
    if (c == 0) {  // lanes g=0..3 hold l[q=q0+qq*16+4g+r] (all cols equal)
      #pragma unroll
      for (int r = 0; r < 4; ++r)
        Lpart[prow + q0 + qq * 16 + 4 * g + r] = ol[qq][r];
    }
  }
}

// ---------------------------------------------------------------------------
// FF1 fused with split-combine: block = 32 rows x 512 N-cols.
// Stage: combine 4 splits of Opart + normalize -> A panels in LDS (32 KB).
// Compute: 4 waves x 128 N-cols, 16 ks x 16 MFMA. grid 256, block 256.
// ---------------------------------------------------------------------------
__global__ __launch_bounds__(256) void k_ff1(
    const __hip_bfloat16* __restrict__ Opart,
    const float* __restrict__ Lpart,
    const __hip_bfloat16* __restrict__ W1f,
    const float* __restrict__ b1,
    __hip_bfloat16* __restrict__ F1f) {
  __shared__ __hip_bfloat16 Asm[2][16][64][8];   // 32 KB
  __shared__ float linv_lds[32][8];              // 1 KB
  const int tid = threadIdx.x;
  const int bid = blockIdx.x;
  const int mp2 = bid >> 1;            // 0..127: 32-row strip
  const int nh  = bid & 1;             // N half (512 cols)
  constexpr size_t LSP = (size_t)16 * S;
  constexpr size_t OSP = (size_t)16 * S * HD;

  {  // per-(row,head) 1/l
    const int rr = tid >> 3;           // 0..31
    const int h  = tid & 7;
    const int m  = mp2 * 32 + rr;
    const int n  = m >> 11, q = m & 2047;
    float lt = 0.f;
    #pragma unroll
    for (int sp = 0; sp < SPLIT; ++sp)
      lt += Lpart[sp * LSP + (size_t)(n * 8 + h) * 2048 + q];
    linv_lds[rr][h] = 1.0f / lt;
  }
  __syncthreads();

  #pragma unroll
  for (int it = 0; it < 8; ++it) {     // stage A panels
    const int gi = it * 256 + tid;     // 0..2047
    const int pp = gi >> 10;
    const int ks = (gi >> 6) & 15;
    const int ll = gi & 63;
    const int rr = ll & 15, gg = ll >> 4;
    const int m = mp2 * 32 + pp * 16 + rr;
    const int n = m >> 11, q = m & 2047;
    const int h = ks >> 1;
    const int d0 = (ks & 1) * 32 + gg * 8;
    const float linv = linv_lds[pp * 16 + rr][h];
    float s0 = 0.f, s1 = 0.f, s2 = 0.f, s3 = 0.f,
          s4 = 0.f, s5 = 0.f, s6 = 0.f, s7 = 0.f;
    #pragma unroll
    for (int sp = 0; sp < SPLIT; ++sp) {
      const uint4 u = *(const uint4*)&Opart[sp * OSP +
          ((size_t)(n * 8 + h) * 2048 + q) * 64 + d0];
      s0 += bfu2f(u.x); s1 += bfu2f(u.x >> 16);
      s2 += bfu2f(u.y); s3 += bfu2f(u.y >> 16);
      s4 += bfu2f(u.z); s5 += bfu2f(u.z >> 16);
      s6 += bfu2f(u.w); s7 += bfu2f(u.w >> 16);
    }
    uint4 pk;
    pk.x = pack_bf2(s0 * linv, s1 * linv);
    pk.y = pack_bf2(s2 * linv, s3 * linv);
    pk.z = pack_bf2(s4 * linv, s5 * linv);
    pk.w = pack_bf2(s6 * linv, s7 * linv);
    *(uint4*)&Asm[pp][ks][ll][0] = pk;
  }
  __syncthreads();

  const int w = tid >> 6, l = tid & 63;
  const int c = l & 15, g = l >> 4;
  f32x4 acc[2][8];
  #pragma unroll
  for (int pp = 0; pp < 2; ++pp)
    #pragma unroll
    for (int i = 0; i < 8; ++i) acc[pp][i] = f32x4{0.f, 0.f, 0.f, 0.f};

  #pragma unroll 4
  for (int ks = 0; ks < 16; ++ks) {
    const bf16x8 af0 = *(const bf16x8*)&Asm[0][ks][l][0];
    const bf16x8 af1 = *(const bf16x8*)&Asm[1][ks][l][0];
    #pragma unroll
    for (int dt = 0; dt < 8; ++dt) {
      const bf16x8 wf = *(const bf16x8*)&W1f[
          (((size_t)(nh * 32 + w * 8 + dt) * 16 + ks) * 64 + l) * 8];
      acc[0][dt] = mfma16(wf, af0, acc[0][dt]);
      acc[1][dt] = mfma16(wf, af1, acc[1][dt]);
    }
  }

  #pragma unroll
  for (int pp = 0; pp < 2; ++pp) {
    const int mpo = mp2 * 2 + pp;
    #pragma unroll
    for (int dt = 0; dt < 8; ++dt) {
      const int nn0 = nh * 512 + w * 128 + dt * 16 + 4 * g;
      const int ks2 = nn0 >> 5;
      const int lw  = c + ((nn0 & 31) >> 3) * 16;
      const int jb  = nn0 & 7;
      uint2 pk;
      pk.x = pack_bf2(fmaxf(acc[pp][dt][0] + b1[nn0 + 0], 0.f),
                      fmaxf(acc[pp][dt][1] + b1[nn0 + 1], 0.f));
      pk.y = pack_bf2(fmaxf(acc[pp][dt][2] + b1[nn0 + 2], 0.f),
                      fmaxf(acc[pp][dt][3] + b1[nn0 + 3], 0.f));
      *(uint2*)&F1f[(((size_t)mpo * 32 + ks2) * 64 + lw) * 8 + jb] = pk;
    }
  }
}

// ---------------------------------------------------------------------------
// FF2 + bias + residual -> out fp32 [n][c][s]. grid 256 x 256 thr; wave w
// owns output-channel strip dt=w over full K (2 interleaved acc chains).
// ---------------------------------------------------------------------------
__global__ __launch_bounds__(256) void k_ff2(
    const __hip_bfloat16* __restrict__ F1f,
    const __hip_bfloat16* __restrict__ W2f,
    const float* __restrict__ b2,
    const float* __restrict__ x,
    float* __restrict__ out) {
  __shared__ float ot[64][17];
  const int tid = threadIdx.x, w = tid >> 6, l = tid & 63;
  const int c = l & 15, g = l >> 4;
  const int mp = blockIdx.x;           // 0..255 (16-row strip)

  f32x4 acc0 = f32x4{0.f, 0.f, 0.f, 0.f};
  f32x4 acc1 = f32x4{0.f, 0.f, 0.f, 0.f};
  #pragma unroll 8
  for (int ks = 0; ks < 32; ks += 2) {
    const bf16x8 af0 = *(const bf16x8*)&F1f[(((size_t)mp * 32 + ks) * 64 + l) * 8];
    const bf16x8 wf0 = *(const bf16x8*)&W2f[((w * 32 + ks) * 64 + l) * 8];
    acc0 = mfma16(wf0, af0, acc0);
    const bf16x8 af1 = *(const bf16x8*)&F1f[(((size_t)mp * 32 + ks + 1) * 64 + l) * 8];
    const bf16x8 wf1 = *(const bf16x8*)&W2f[((w * 32 + ks + 1) * 64 + l) * 8];
    acc1 = mfma16(wf1, af1, acc1);
  }
  #pragma unroll
  for (int r = 0; r < 4; ++r)
    ot[w * 16 + 4 * g + r][c] = acc0[r] + acc1[r];   // [ch][s-offset]
  __syncthreads();

  const int ch = tid >> 2, si = (tid & 3) * 4;
  const int m0 = mp * 16;
  const int n = m0 >> 11, s0 = (m0 & 2047) + si;
  const size_t base = ((size_t)n * C + ch) * S + s0;
  const float bb = b2[ch];
  const float4 xv = *(const float4*)&x[base];
  float4 ov;
  ov.x = ot[ch][si + 0] + bb + xv.x;
  ov.y = ot[ch][si + 1] + bb + xv.y;
  ov.z = ot[ch][si + 2] + bb + xv.z;
  ov.w = ot[ch][si + 3] + bb + xv.w;
  *(float4*)&out[base] = ov;
}

// ---------------------------------------------------------------------------
extern "C" void kernel_launch(void* const* d_in, const int* in_sizes, int n_in,
                              void* d_out, int out_size, void* d_ws, size_t ws_size,
                              hipStream_t stream) {
  const float* x  = (const float*)d_in[0];
  const float* Wq = (const float*)d_in[1];
  const float* bq = (const float*)d_in[2];
  const float* Wk = (const float*)d_in[3];
  const float* bk = (const float*)d_in[4];
  const float* Wv = (const float*)d_in[5];
  const float* bv = (const float*)d_in[6];
  const float* W1 = (const float*)d_in[7];
  const float* b1 = (const float*)d_in[8];
  const float* W2 = (const float*)d_in[9];
  const float* b2 = (const float*)d_in[10];
  float* out = (float*)d_out;

  char* wsb = (char*)d_ws;
  const size_t KB = 1024, MB = 1024 * 1024;
  __hip_bfloat16* xbf = (__hip_bfloat16*)(wsb);                    // 512 KiB
  __hip_bfloat16* Wqf = (__hip_bfloat16*)(wsb + 512 * KB);         // 64 KiB
  __hip_bfloat16* Wkf = (__hip_bfloat16*)(wsb + 576 * KB);
  __hip_bfloat16* Wvf = (__hip_bfloat16*)(wsb + 640 * KB);
  __hip_bfloat16* W1f = (__hip_bfloat16*)(wsb + 768 * KB);         // 1 MiB
  __hip_bfloat16* W2f = (__hip_bfloat16*)(wsb + 1792 * KB);        // 128 KiB
  __hip_bfloat16* Qf  = (__hip_bfloat16*)(wsb + 2  * MB);          // 4 MiB
  __hip_bfloat16* Kf  = (__hip_bfloat16*)(wsb + 6  * MB);
  __hip_bfloat16* Vf  = (__hip_bfloat16*)(wsb + 10 * MB);
  __hip_bfloat16* F1f = (__hip_bfloat16*)(wsb + 18 * MB);          // 8 MiB
  __hip_bfloat16* Opart = (__hip_bfloat16*)(wsb + 26 * MB);        // 16 MiB
  float*          Lpart = (float*)(wsb + 42 * MB);                 // 512 KiB

  k_pre<<<464, 256, 0, stream>>>(Wq, Wk, Wv, W1, W2, x,
                                 Wqf, Wkf, Wvf, W1f, W2f, xbf);
  k_qkv<<<dim3(24, 64), 256, 0, stream>>>(xbf, Wqf, bq, Wkf, bk, Wvf, bv,
                                          Qf, Kf, Vf);
  k_attn<<<16 * SPLIT * 32, 128, 0, stream>>>(Qf, Kf, Vf, Opart, Lpart);
  k_ff1<<<256, 256, 0, stream>>>(Opart, Lpart, W1f, b1, F1f);
  k_ff2<<<256, 256, 0, stream>>>(F1f, W2f, b2, x, out);
}

// Round 9
// 131.773 us; speedup vs baseline: 1.1841x; 1.1841x over previous
//
#include <hip/hip_runtime.h>
#include <hip/hip_bf16.h>

constexpr int S  = 2048;
constexpr int C  = 64;
constexpr int NH = 8;
constexpr int HD = 64;
constexpr int TD = 512;
constexpr int FF = 1024;
constexpr int NB = 2;
constexpr int SPLIT  = 4;
constexpr int KTILES = S / SPLIT / 64;   // 8

typedef __bf16 bf16x8 __attribute__((ext_vector_type(8)));
typedef float  f32x4  __attribute__((ext_vector_type(4)));

__device__ __forceinline__ f32x4 mfma16(bf16x8 a, bf16x8 b, f32x4 c) {
  return __builtin_amdgcn_mfma_f32_16x16x32_bf16(a, b, c, 0, 0, 0);
}

__device__ __forceinline__ unsigned int pack_bf2(float a, float b) {
  unsigned short ua = __builtin_bit_cast(unsigned short, (__bf16)a);
  unsigned short ub = __builtin_bit_cast(unsigned short, (__bf16)b);
  return (unsigned int)ua | ((unsigned int)ub << 16);
}

__device__ __forceinline__ float bfu2f(unsigned int u) {
  return __builtin_bit_cast(float, (u & 0xffffu) << 16);
}

// Panel layout: frag[p][ks][lane][8], elem = M[p*16 + (l&15)][ks*32 + (l>>4)*8 + j].
// A wave's fragment load = one contiguous 1KB chunk.

// ---------------------------------------------------------------------------
// Fused preprocessing: blocks 0..335 convert the 5 weight matrices to panel
// layout; blocks 336..463 transpose/convert x -> xbf panels.
// ---------------------------------------------------------------------------
__device__ __forceinline__ void cvt_panel(const float* __restrict__ src,
                                          __hip_bfloat16* __restrict__ dst,
                                          int off, int Wd) {
  const int w8 = Wd >> 3;
  const int r  = off / w8;
  const int k8 = off - r * w8;
  const float4 v0 = *(const float4*)(src + (size_t)r * Wd + k8 * 8);
  const float4 v1 = *(const float4*)(src + (size_t)r * Wd + k8 * 8 + 4);
  const int dc = ((r >> 4) * (Wd >> 5) + (k8 >> 2)) * 64 + (k8 & 3) * 16 + (r & 15);
  uint4 pk;
  pk.x = pack_bf2(v0.x, v0.y); pk.y = pack_bf2(v0.z, v0.w);
  pk.z = pack_bf2(v1.x, v1.y); pk.w = pack_bf2(v1.z, v1.w);
  *(uint4*)&dst[dc * 8] = pk;
}

__global__ __launch_bounds__(256) void k_pre(
    const float* __restrict__ Wq, const float* __restrict__ Wk,
    const float* __restrict__ Wv, const float* __restrict__ W1,
    const float* __restrict__ W2, const float* __restrict__ x,
    __hip_bfloat16* __restrict__ Wqf, __hip_bfloat16* __restrict__ Wkf,
    __hip_bfloat16* __restrict__ Wvf, __hip_bfloat16* __restrict__ W1f,
    __hip_bfloat16* __restrict__ W2f, __hip_bfloat16* __restrict__ xbf) {
  const int b = blockIdx.x;
  if (b < 336) {
    const int q = b * 256 + threadIdx.x;   // 0..86015
    if      (q < 4096)  cvt_panel(Wq, Wqf, q,         C);    // 512x64
    else if (q < 8192)  cvt_panel(Wk, Wkf, q - 4096,  C);
    else if (q < 12288) cvt_panel(Wv, Wvf, q - 8192,  C);
    else if (q < 77824) cvt_panel(W1, W1f, q - 12288, TD);   // 1024x512
    else                cvt_panel(W2, W2f, q - 77824, FF);   // 64x1024
  } else {
    const int id = (b - 336) * 256 + threadIdx.x;  // 0..32767
    const int k8 = id >> 12;
    const int m  = id & 4095;
    const int n  = m >> 11, s = m & 2047;
    float v[8];
    #pragma unroll
    for (int j = 0; j < 8; ++j)
      v[j] = x[(size_t)(n * C + k8 * 8 + j) * S + s];
    const int p = m >> 4, ks = k8 >> 2, l = (m & 15) + (k8 & 3) * 16;
    uint4 pk;
    pk.x = pack_bf2(v[0], v[1]); pk.y = pack_bf2(v[2], v[3]);
    pk.z = pack_bf2(v[4], v[5]); pk.w = pack_bf2(v[6], v[7]);
    *(uint4*)&xbf[((p * 2 + ks) * 64 + l) * 8] = pk;
  }
}

// ---------------------------------------------------------------------------
// QKV projection; panel layout in and out. Q scaled by log2(e)/8.
// ---------------------------------------------------------------------------
__global__ __launch_bounds__(256) void k_qkv(
    const __hip_bfloat16* __restrict__ xbf,
    const __hip_bfloat16* __restrict__ Wqf, const float* __restrict__ bq,
    const __hip_bfloat16* __restrict__ Wkf, const float* __restrict__ bk,
    const __hip_bfloat16* __restrict__ Wvf, const float* __restrict__ bv,
    __hip_bfloat16* __restrict__ Qf, __hip_bfloat16* __restrict__ Kf,
    __hip_bfloat16* __restrict__ Vf) {
  const int t = threadIdx.x, w = t >> 6, l = t & 63;
  const int c = l & 15, g = l >> 4;
  const int m0 = blockIdx.y * 64 + w * 16;
  const int xcol = blockIdx.x, which = xcol >> 3, h = xcol & 7;

  const __hip_bfloat16* Wf = (which == 0) ? Wqf : (which == 1) ? Wkf : Wvf;
  const float*        bias = (which == 0) ? bq  : (which == 1) ? bk  : bv;

  f32x4 acc[4];
  #pragma unroll
  for (int i = 0; i < 4; ++i) acc[i] = f32x4{0.f, 0.f, 0.f, 0.f};

  #pragma unroll
  for (int ks = 0; ks < 2; ++ks) {
    const bf16x8 af = *(const bf16x8*)&xbf[(((m0 >> 4) * 2 + ks) * 64 + l) * 8];
    #pragma unroll
    for (int dt = 0; dt < 4; ++dt) {
      const bf16x8 wf =
          *(const bf16x8*)&Wf[(((h * 4 + dt) * 2 + ks) * 64 + l) * 8];
      acc[dt] = mfma16(wf, af, acc[dt]);  // out[m0+c][h*64 + dt*16 + 4g + r]
    }
  }

  const int m = m0 + c;
  const int nb_ = m >> 11, s = m & 2047;
  const size_t hbq = (size_t)(nb_ * 8 + h) * (S * HD);

  if (which < 2) {
    const float scl = (which == 0) ? 0.1803368801f : 1.0f;  // log2(e)/8
    __hip_bfloat16* Of = ((which == 0) ? Qf : Kf) + hbq;
    const int sp16 = s >> 4;
    #pragma unroll
    for (int dt = 0; dt < 4; ++dt) {
      const int ks = dt >> 1;
      const int lw = c + ((dt & 1) * 2 + (g >> 1)) * 16;
      const int jb = (4 * g) & 7;
      const int d0 = dt * 16 + 4 * g;
      uint2 pk;
      pk.x = pack_bf2((acc[dt][0] + bias[h * 64 + d0 + 0]) * scl,
                      (acc[dt][1] + bias[h * 64 + d0 + 1]) * scl);
      pk.y = pack_bf2((acc[dt][2] + bias[h * 64 + d0 + 2]) * scl,
                      (acc[dt][3] + bias[h * 64 + d0 + 3]) * scl);
      *(uint2*)&Of[((sp16 * 2 + ks) * 64 + lw) * 8 + jb] = pk;
    }
  } else {
    __hip_bfloat16* Vfh = Vf + hbq;
    const int kc = s >> 5, jj = s & 7, lhi = ((s & 31) >> 3) * 16;
    #pragma unroll
    for (int dt = 0; dt < 4; ++dt)
      #pragma unroll
      for (int r = 0; r < 4; ++r) {
        const float v = acc[dt][r] + bias[h * 64 + dt * 16 + 4 * g + r];
        Vfh[((dt * 64 + kc) * 64 + (4 * g + r + lhi)) * 8 + jj] =
            __float2bfloat16(v);
      }
  }
}

// ---------------------------------------------------------------------------
// Flash attention. 2 waves/block, QBLK=32/wave, SPLIT=4. Parity-double-
// buffered P_lds (one wave_barrier/tile). No max subtraction. Softmax
// denominator l via MFMA with all-ones B. s_setprio(1) around MFMA clusters.
// ---------------------------------------------------------------------------
__global__ __launch_bounds__(128, 4) void k_attn(
    const __hip_bfloat16* __restrict__ Qf,
    const __hip_bfloat16* __restrict__ Kf,
    const __hip_bfloat16* __restrict__ Vf,
    __hip_bfloat16* __restrict__ Opart, float* __restrict__ Lpart) {
  __shared__ unsigned short P_lds[2][2][2][16][72];  // [par][w][qq]

  const int t = threadIdx.x, w = t >> 6, l = t & 63;
  const int c = l & 15, g = l >> 4;
  const int bid = blockIdx.x;
  const int hb  = bid & 15;
  const int sp  = (bid >> 4) & (SPLIT - 1);
  const int q0  = (bid >> 6) * 64 + w * 32;
  const size_t hbase = (size_t)hb * (S * HD);

  bf16x8 ones;
  #pragma unroll
  for (int j = 0; j < 8; ++j) ones[j] = (__bf16)1.0f;

  bf16x8 qf[2][2];
  const int qp0 = q0 >> 4;
  #pragma unroll
  for (int qq = 0; qq < 2; ++qq)
    #pragma unroll
    for (int ks = 0; ks < 2; ++ks)
      qf[qq][ks] =
          *(const bf16x8*)&Qf[hbase + (((qp0 + qq) * 2 + ks) * 64 + l) * 8];

  f32x4 o[2][4];
  f32x4 ol[2];
  #pragma unroll
  for (int qq = 0; qq < 2; ++qq) {
    ol[qq] = f32x4{0.f, 0.f, 0.f, 0.f};
    #pragma unroll
    for (int i = 0; i < 4; ++i) o[qq][i] = f32x4{0.f, 0.f, 0.f, 0.f};
  }

  const int kb = sp * (S / SPLIT);

  #pragma unroll
  for (int it = 0; it < KTILES; ++it) {
    const int k0  = kb + it * 64;
    const int par = it & 1;
    const int kp0 = k0 >> 4, kc0 = k0 >> 5;

    // ---- QK^T (swapped): st[qq][t4][r] = S^T[kv=t4*16+4g+r][q=q0+qq*16+c]
    f32x4 st[2][4];
    #pragma unroll
    for (int qq = 0; qq < 2; ++qq)
      #pragma unroll
      for (int i = 0; i < 4; ++i) st[qq][i] = f32x4{0.f, 0.f, 0.f, 0.f};
    __builtin_amdgcn_s_setprio(1);
    #pragma unroll
    for (int t4 = 0; t4 < 4; ++t4) {
      const bf16x8 ka0 =
          *(const bf16x8*)&Kf[hbase + (((kp0 + t4) * 2 + 0) * 64 + l) * 8];
      const bf16x8 ka1 =
          *(const bf16x8*)&Kf[hbase + (((kp0 + t4) * 2 + 1) * 64 + l) * 8];
      st[0][t4] = mfma16(ka0, qf[0][0], st[0][t4]);
      st[0][t4] = mfma16(ka1, qf[0][1], st[0][t4]);
      st[1][t4] = mfma16(ka0, qf[1][0], st[1][t4]);
      st[1][t4] = mfma16(ka1, qf[1][1], st[1][t4]);
    }
    __builtin_amdgcn_s_setprio(0);

    // ---- P = exp2(s) (no max), P^T scatter into parity buffer
    #pragma unroll
    for (int qq = 0; qq < 2; ++qq)
      #pragma unroll
      for (int t4 = 0; t4 < 4; ++t4) {
        const float e0 = __builtin_amdgcn_exp2f(st[qq][t4][0]);
        const float e1 = __builtin_amdgcn_exp2f(st[qq][t4][1]);
        const float e2 = __builtin_amdgcn_exp2f(st[qq][t4][2]);
        const float e3 = __builtin_amdgcn_exp2f(st[qq][t4][3]);
        uint2 pk;
        pk.x = pack_bf2(e0, e1);
        pk.y = pack_bf2(e2, e3);
        *(uint2*)&P_lds[par][w][qq][c][t4 * 16 + g * 4] = pk;
      }

    __builtin_amdgcn_wave_barrier();   // write->read ordering (wave-local)

    // ---- PV (+ l via ones-MFMA): o[qq][dt] += P[q][kv] * V^T[d][kv]
    __builtin_amdgcn_s_setprio(1);
    #pragma unroll
    for (int ks = 0; ks < 2; ++ks) {
      const bf16x8 pf0 = *(const bf16x8*)&P_lds[par][w][0][c][ks * 32 + g * 8];
      const bf16x8 pf1 = *(const bf16x8*)&P_lds[par][w][1][c][ks * 32 + g * 8];
      ol[0] = mfma16(pf0, ones, ol[0]);
      ol[1] = mfma16(pf1, ones, ol[1]);
      #pragma unroll
      for (int dt = 0; dt < 4; ++dt) {
        const bf16x8 vfr =
            *(const bf16x8*)&Vf[hbase + ((dt * 64 + kc0 + ks) * 64 + l) * 8];
        o[0][dt] = mfma16(pf0, vfr, o[0][dt]);
        o[1][dt] = mfma16(pf1, vfr, o[1][dt]);
      }
    }
    __builtin_amdgcn_s_setprio(0);
    // no trailing barrier: next iteration writes the other parity buffer
  }

  const size_t prow = ((size_t)sp * 16 + hb) * S;
  #pragma unroll
  for (int qq = 0; qq < 2; ++qq) {
    #pragma unroll
    for (int r = 0; r < 4; ++r) {
      __hip_bfloat16* Op = Opart + (prow + q0 + qq * 16 + 4 * g + r) * HD + c;
      Op[0]  = __float2bfloat16(o[qq][0][r]);
      Op[16] = __float2bfloat16(o[qq][1][r]);
      Op[32] = __float2bfloat16(o[qq][2][r]);
      Op[48] = __float2bfloat16(o[qq][3][r]);
    }
    if (c == 0) {  // lanes g=0..3 hold l[q=q0+qq*16+4g+r] (all cols equal)
      #pragma unroll
      for (int r = 0; r < 4; ++r)
        Lpart[prow + q0 + qq * 16 + 4 * g + r] = ol[qq][r];
    }
  }
}

// ---------------------------------------------------------------------------
// Combine 4 splits + normalize -> ATf (A-panel layout over [4096][512]).
// Coalesced on both sides: 16 lanes read 256B contiguous per row.
// ---------------------------------------------------------------------------
__global__ __launch_bounds__(256) void k_comb(
    const __hip_bfloat16* __restrict__ Opart,
    const float* __restrict__ Lpart,
    __hip_bfloat16* __restrict__ ATf) {
  const int gid = blockIdx.x * 256 + threadIdx.x;   // 0..524287
  const int r = gid >> 4, dq = (gid & 15) * 4;
  constexpr size_t OSP = (size_t)16 * S * HD;
  constexpr size_t LSP = (size_t)16 * S;

  float l = 0.f;
  float s0 = 0.f, s1 = 0.f, s2 = 0.f, s3 = 0.f;
  #pragma unroll
  for (int sp = 0; sp < SPLIT; ++sp) {
    l += Lpart[sp * LSP + r];
    const uint2 u = *(const uint2*)&Opart[sp * OSP + (size_t)r * HD + dq];
    s0 += bfu2f(u.x); s1 += bfu2f(u.x >> 16);
    s2 += bfu2f(u.y); s3 += bfu2f(u.y >> 16);
  }
  const float inv = 1.0f / l;

  const int hb = r >> 11, q = r & 2047;
  const int n = hb >> 3, h = hb & 7;
  const int m = n * S + q, k = h * 64 + dq;
  const int mp = m >> 4, ks = k >> 5;
  const int lw = (m & 15) + ((k & 31) >> 3) * 16, j = k & 7;
  uint2 pk;
  pk.x = pack_bf2(s0 * inv, s1 * inv);
  pk.y = pack_bf2(s2 * inv, s3 * inv);
  *(uint2*)&ATf[((mp * 16 + ks) * 64 + lw) * 8 + j] = pk;
}

// ---------------------------------------------------------------------------
// FF1 = relu(A @ W1^T + b1) -> F1f panels. grid (8,64), 4 waves; each wave a
// 16x128 out strip (8 acc chains for ILP).
// ---------------------------------------------------------------------------
__global__ __launch_bounds__(256) void k_ff1(
    const __hip_bfloat16* __restrict__ ATf,
    const __hip_bfloat16* __restrict__ W1f,
    const float* __restrict__ b1,
    __hip_bfloat16* __restrict__ F1f) {
  const int t = threadIdx.x, w = t >> 6, l = t & 63;
  const int c = l & 15, g = l >> 4;
  const int mp = blockIdx.y * 4 + w;
  const int bx = blockIdx.x;

  f32x4 acc[8];
  #pragma unroll
  for (int i = 0; i < 8; ++i) acc[i] = f32x4{0.f, 0.f, 0.f, 0.f};

  #pragma unroll
  for (int ks = 0; ks < 16; ++ks) {
    const bf16x8 af = *(const bf16x8*)&ATf[((mp * 16 + ks) * 64 + l) * 8];
    #pragma unroll
    for (int dt = 0; dt < 8; ++dt) {
      const bf16x8 wf =
          *(const bf16x8*)&W1f[(((bx * 8 + dt) * 16 + ks) * 64 + l) * 8];
      acc[dt] = mfma16(wf, af, acc[dt]);  // out[mp*16+c][bx*128 + dt*16 + 4g+r]
    }
  }

  #pragma unroll
  for (int dt = 0; dt < 8; ++dt) {
    const int ks2 = bx * 4 + (dt >> 1);
    const int lw  = c + ((dt & 1) * 2 + (g >> 1)) * 16;
    const int jb  = (4 * g) & 7;
    const int nn  = bx * 128 + dt * 16 + 4 * g;
    uint2 pk;
    pk.x = pack_bf2(fmaxf(acc[dt][0] + b1[nn + 0], 0.f),
                    fmaxf(acc[dt][1] + b1[nn + 1], 0.f));
    pk.y = pack_bf2(fmaxf(acc[dt][2] + b1[nn + 2], 0.f),
                    fmaxf(acc[dt][3] + b1[nn + 3], 0.f));
    *(uint2*)&F1f[((mp * 32 + ks2) * 64 + lw) * 8 + jb] = pk;
  }
}

// ---------------------------------------------------------------------------
// FF2 + bias + residual -> out fp32 [n][c][s]. grid 256 x 256 thr; wave w
// owns output-channel strip dt=w over full K (2 interleaved acc chains).
// ---------------------------------------------------------------------------
__global__ __launch_bounds__(256) void k_ff2(
    const __hip_bfloat16* __restrict__ F1f,
    const __hip_bfloat16* __restrict__ W2f,
    const float* __restrict__ b2,
    const float* __restrict__ x,
    float* __restrict__ out) {
  __shared__ float ot[64][17];
  const int tid = threadIdx.x, w = tid >> 6, l = tid & 63;
  const int c = l & 15, g = l >> 4;
  const int mp = blockIdx.x;           // 0..255 (16-row strip)

  f32x4 acc0 = f32x4{0.f, 0.f, 0.f, 0.f};
  f32x4 acc1 = f32x4{0.f, 0.f, 0.f, 0.f};
  #pragma unroll 8
  for (int ks = 0; ks < 32; ks += 2) {
    const bf16x8 af0 = *(const bf16x8*)&F1f[(((size_t)mp * 32 + ks) * 64 + l) * 8];
    const bf16x8 wf0 = *(const bf16x8*)&W2f[((w * 32 + ks) * 64 + l) * 8];
    acc0 = mfma16(wf0, af0, acc0);
    const bf16x8 af1 = *(const bf16x8*)&F1f[(((size_t)mp * 32 + ks + 1) * 64 + l) * 8];
    const bf16x8 wf1 = *(const bf16x8*)&W2f[((w * 32 + ks + 1) * 64 + l) * 8];
    acc1 = mfma16(wf1, af1, acc1);
  }
  #pragma unroll
  for (int r = 0; r < 4; ++r)
    ot[w * 16 + 4 * g + r][c] = acc0[r] + acc1[r];   // [ch][s-offset]
  __syncthreads();

  const int ch = tid >> 2, si = (tid & 3) * 4;
  const int m0 = mp * 16;
  const int n = m0 >> 11, s0 = (m0 & 2047) + si;
  const size_t base = ((size_t)n * C + ch) * S + s0;
  const float bb = b2[ch];
  const float4 xv = *(const float4*)&x[base];
  float4 ov;
  ov.x = ot[ch][si + 0] + bb + xv.x;
  ov.y = ot[ch][si + 1] + bb + xv.y;
  ov.z = ot[ch][si + 2] + bb + xv.z;
  ov.w = ot[ch][si + 3] + bb + xv.w;
  *(float4*)&out[base] = ov;
}

// ---------------------------------------------------------------------------
extern "C" void kernel_launch(void* const* d_in, const int* in_sizes, int n_in,
                              void* d_out, int out_size, void* d_ws, size_t ws_size,
                              hipStream_t stream) {
  const float* x  = (const float*)d_in[0];
  const float* Wq = (const float*)d_in[1];
  const float* bq = (const float*)d_in[2];
  const float* Wk = (const float*)d_in[3];
  const float* bk = (const float*)d_in[4];
  const float* Wv = (const float*)d_in[5];
  const float* bv = (const float*)d_in[6];
  const float* W1 = (const float*)d_in[7];
  const float* b1 = (const float*)d_in[8];
  const float* W2 = (const float*)d_in[9];
  const float* b2 = (const float*)d_in[10];
  float* out = (float*)d_out;

  char* wsb = (char*)d_ws;
  const size_t KB = 1024, MB = 1024 * 1024;
  __hip_bfloat16* xbf = (__hip_bfloat16*)(wsb);                    // 512 KiB
  __hip_bfloat16* Wqf = (__hip_bfloat16*)(wsb + 512 * KB);         // 64 KiB
  __hip_bfloat16* Wkf = (__hip_bfloat16*)(wsb + 576 * KB);
  __hip_bfloat16* Wvf = (__hip_bfloat16*)(wsb + 640 * KB);
  __hip_bfloat16* W1f = (__hip_bfloat16*)(wsb + 768 * KB);         // 1 MiB
  __hip_bfloat16* W2f = (__hip_bfloat16*)(wsb + 1792 * KB);        // 128 KiB
  __hip_bfloat16* Qf  = (__hip_bfloat16*)(wsb + 2  * MB);          // 4 MiB
  __hip_bfloat16* Kf  = (__hip_bfloat16*)(wsb + 6  * MB);
  __hip_bfloat16* Vf  = (__hip_bfloat16*)(wsb + 10 * MB);
  __hip_bfloat16* ATf = (__hip_bfloat16*)(wsb + 14 * MB);          // 4 MiB
  __hip_bfloat16* F1f = (__hip_bfloat16*)(wsb + 18 * MB);          // 8 MiB
  __hip_bfloat16* Opart = (__hip_bfloat16*)(wsb + 26 * MB);        // 16 MiB
  float*          Lpart = (float*)(wsb + 42 * MB);                 // 512 KiB

  k_pre<<<464, 256, 0, stream>>>(Wq, Wk, Wv, W1, W2, x,
                                 Wqf, Wkf, Wvf, W1f, W2f, xbf);
  k_qkv<<<dim3(24, 64), 256, 0, stream>>>(xbf, Wqf, bq, Wkf, bk, Wvf, bv,
                                          Qf, Kf, Vf);
  k_attn<<<16 * SPLIT * 32, 128, 0, stream>>>(Qf, Kf, Vf, Opart, Lpart);
  k_comb<<<2048, 256, 0, stream>>>(Opart, Lpart, ATf);
  k_ff1<<<dim3(8, 64), 256, 0, stream>>>(ATf, W1f, b1, F1f);
  k_ff2<<<256, 256, 0, stream>>>(F1f, W2f, b2, x, out);
}